// Round 15
// baseline (139.678 us; speedup 1.0000x reference)
//
#include <hip/hip_runtime.h>

#define TTOK 4096
#define NEXP 8
#define DDIM 512
#define FDIM 2048
#define HROWS 8576   // padded-compact row allocation (max used 8440 + slack)

typedef __attribute__((ext_vector_type(8))) short short8;
typedef __attribute__((ext_vector_type(4))) float floatx4;

#define BAR()  __builtin_amdgcn_s_barrier()
#define SBAR() __builtin_amdgcn_sched_barrier(0)

__device__ __forceinline__ ushort f2b(float f) {
  unsigned u = __float_as_uint(f);
  u += 0x7fffu + ((u >> 16) & 1u);   // round-to-nearest-even bf16
  return (ushort)(u >> 16);
}

__device__ __forceinline__ void load16(void* lds, const void* g) {
  __builtin_amdgcn_global_load_lds(
      (const __attribute__((address_space(1))) unsigned int*)g,
      (__attribute__((address_space(3))) unsigned int*)lds, 16, 0, 0);
}

// Fragment-tile layout (16x16x32 MFMA operands): matrix [R][C] stored as
// 16-row x 32-col tiles of 1KB. Tile (rt,kt) at ((rt*(C/32))+kt)*512 elems.
// elem (r,c): slot = (r&15) + 16*((c>>3)&3), ushort idx = slot*8+(c&7).
// Wave fragment read = lane l reads tile+l*16B -> conflict-free ds_read_b128.

// ---------------- fat front: logits+top2+zero-out (blocks 0..1023) | w1/w3 cvt
__global__ __launch_bounds__(256) void k_front(
    const float* __restrict__ x, const float* __restrict__ gw,
    float* __restrict__ logits, int* __restrict__ tok_e,
    float2* __restrict__ tok_w, float* __restrict__ outz,
    const float* __restrict__ w1, ushort* __restrict__ w1t,
    const float* __restrict__ w3, ushort* __restrict__ w3t)
{
  __shared__ ushort sm[4096];
  const int tid = threadIdx.x;
  if (blockIdx.x < TTOK / 4) {
    // zero the out rows for these 4 tokens (replaces hipMemsetAsync)
    float4 zz = {0.f, 0.f, 0.f, 0.f};
    float4* orow = (float4*)(outz + (size_t)blockIdx.x * 4 * DDIM);
    orow[tid] = zz;
    orow[tid + 256] = zz;
    const int lane = tid & 63;
    const int t = blockIdx.x * 4 + (tid >> 6);
    float xv[8];
#pragma unroll
    for (int i = 0; i < 8; ++i) xv[i] = x[(size_t)t * DDIM + lane + 64 * i];
    float lg[8];
#pragma unroll
    for (int e = 0; e < 8; ++e) {
      float a = 0.f;
#pragma unroll
      for (int i = 0; i < 8; ++i) a += xv[i] * gw[e * DDIM + lane + 64 * i];
#pragma unroll
      for (int s = 32; s; s >>= 1) a += __shfl_xor(a, s, 64);
      lg[e] = a;
    }
    if (lane < 8) logits[(size_t)t * 8 + lane] = lg[lane];
    if (lane == 0) {
      int i0 = 0; float v0 = lg[0];
#pragma unroll
      for (int e = 1; e < 8; ++e) { if (lg[e] > v0) { v0 = lg[e]; i0 = e; } }
      int i1 = -1; float v1 = -3.4e38f;
#pragma unroll
      for (int e = 0; e < 8; ++e) { if (e != i0 && lg[e] > v1) { v1 = lg[e]; i1 = e; } }
      float ex = expf(v1 - v0);
      float inv = 1.f / (1.f + ex);
      tok_e[t] = i0 | (i1 << 4);
      tok_w[t] = make_float2(inv, ex * inv);
    }
    return;
  }
  // w1 / w3 conversion into fragment-tiled layout (C = 512, KT = 16)
  int bid = blockIdx.x - TTOK / 4;             // 0..4095
  const float* src = (bid < 2048) ? w1 : w3;
  ushort* dst = (bid < 2048) ? w1t : w3t;
  if (bid >= 2048) bid -= 2048;
  const int r0 = (bid >> 2) * 32;
  const int c0 = (bid & 3) * 128;
#pragma unroll
  for (int i = 0; i < 4; ++i) {
    int j = i * 1024 + tid * 4;
    int lr = j >> 7, lc = j & 127;
    float4 v = *(const float4*)&src[(size_t)(r0 + lr) * 512 + c0 + lc];
    ushort4 b = { f2b(v.x), f2b(v.y), f2b(v.z), f2b(v.w) };
    int ord = (lr >> 4) * 4 + (lc >> 5);
    int slot = (lr & 15) + 16 * ((lc >> 3) & 3);
    *(ushort4*)&sm[(ord * 64 + slot) * 8 + (lc & 7)] = b;
  }
  __syncthreads();
  const size_t tb0 = ((size_t)(r0 >> 4) * 16 + (c0 >> 5)) * 512;
#pragma unroll
  for (int rt = 0; rt < 2; ++rt)
    *(short8*)&dst[tb0 + (size_t)rt * 16 * 512 + tid * 8] =
        *(const short8*)&sm[rt * 2048 + tid * 8];
}

// ---------------- router pass 2: per-expert compaction, ballot prefix
__global__ __launch_bounds__(1024) void k_build(
    const int* __restrict__ tok_e, const float2* __restrict__ tok_w,
    int* __restrict__ counts, int* __restrict__ lists, float* __restrict__ wts)
{
  const int e = blockIdx.x;
  const int tid = threadIdx.x;
  const int lane = tid & 63, wid = tid >> 6;
  __shared__ int wcnt[16];
  __shared__ int sbase;
  if (tid == 0) sbase = 0;
  __syncthreads();

  for (int c = 0; c < TTOK; c += 1024) {
    int t = c + tid;
    int pe = tok_e[t];
    bool m0 = (pe & 15) == e;
    bool m1 = ((pe >> 4) & 15) == e;
    bool m = m0 || m1;
    unsigned long long b = __ballot(m);
    int lpre = __popcll(b & ((1ull << lane) - 1ull));
    if (lane == 0) wcnt[wid] = __popcll(b);
    __syncthreads();
    int woff = 0;
#pragma unroll
    for (int i = 0; i < 16; ++i) if (i < wid) woff += wcnt[i];
    if (m) {
      float2 w = tok_w[t];
      int pos = sbase + woff + lpre;
      lists[e * TTOK + pos] = t;
      wts[e * TTOK + pos] = m0 ? w.x : w.y;
    }
    __syncthreads();
    if (tid == 0) {
      int s = 0;
#pragma unroll
      for (int i = 0; i < 16; ++i) s += wcnt[i];
      sbase += s;
    }
    __syncthreads();
  }
  if (tid == 0) counts[e] = sbase;
}

// ---------------- gather + f32->bf16: x rows -> compacted fragment-tiled Xg
__global__ __launch_bounds__(256) void k_gather(
    const float* __restrict__ x, const int* __restrict__ counts,
    const int* __restrict__ lists, ushort* __restrict__ Xg)
{
  int pp[9];
  pp[0] = 0;
#pragma unroll
  for (int i = 0; i < 8; ++i) pp[i + 1] = pp[i] + ((counts[i] + 31) & ~31);
  int gid = blockIdx.x * 256 + threadIdx.x;
  int gr = gid >> 6, dg = gid & 63;        // row, 8-col group
  if (gr >= pp[8]) return;
  int e = 0;
  while (e < 7 && gr >= pp[e + 1]) ++e;
  int p = gr - pp[e];
  size_t dst = ((size_t)(gr >> 4) * 16 + (dg >> 2)) * 512
             + ((gr & 15) + 16 * (dg & 3)) * 8;
  short8 o = (short8)0;
  if (p < counts[e]) {
    int t = lists[e * TTOK + p];
    const float* s = x + (size_t)t * DDIM + dg * 8;
    float4 a = *(const float4*)s;
    float4 b = *(const float4*)(s + 4);
    o[0] = f2b(a.x); o[1] = f2b(a.y); o[2] = f2b(a.z); o[3] = f2b(a.w);
    o[4] = f2b(b.x); o[5] = f2b(b.y); o[6] = f2b(b.z); o[7] = f2b(b.w);
  }
  *(short8*)&Xg[dst] = o;
}

// ---------------- fat GEMM1: H = silu(Xg W1^T) * (Xg W3^T)
//                  + w2 cvt, INTERLEAVED (1 cvt 8-round per 2 gemm 8-rounds)
// 8 waves (2x4), 128x128 tile, BK=32, TRIPLE-buffered (depth-2 prefetch),
// counted-vmcnt pipeline + T5 setprio, fragment-tiled LDS (conflict-free)
__global__ __launch_bounds__(512) void k_ffn1(
    const ushort* __restrict__ Xg, const ushort* __restrict__ w1t,
    const ushort* __restrict__ w3t, const int* __restrict__ counts,
    ushort* __restrict__ H,
    const float* __restrict__ w2, ushort* __restrict__ w2t)
{
  // 3 buffers x (X 8KB | W1 8KB | W3 8KB) = 72KB
  __shared__ ushort smem[36864];
  const int tid = threadIdx.x;

  // role by 8-block round: rounds 0,1 of each 3 -> GEMM; round 2 -> w2 cvt.
  const int grp = blockIdx.x >> 3, lane8 = blockIdx.x & 7;
  const int q3 = grp % 3, gq = grp / 3;

  if (q3 == 2) {
    // ---- w2 conversion path (C = 2048, KT = 64), 512 threads
    int bid = gq * 8 + lane8;                  // 0..2047
    ushort* sm = smem;
    const int r0 = (bid >> 4) * 32;
    const int c0 = (bid & 15) * 128;
#pragma unroll
    for (int i = 0; i < 2; ++i) {
      int j = i * 2048 + tid * 4;
      int lr = j >> 7, lc = j & 127;
      float4 v = *(const float4*)&w2[(size_t)(r0 + lr) * 2048 + c0 + lc];
      ushort4 b = { f2b(v.x), f2b(v.y), f2b(v.z), f2b(v.w) };
      int ord = (lr >> 4) * 4 + (lc >> 5);
      int slot = (lr & 15) + 16 * ((lc >> 3) & 3);
      *(ushort4*)&sm[(ord * 64 + slot) * 8 + (lc & 7)] = b;
    }
    __syncthreads();
    const size_t tb0 = ((size_t)(r0 >> 4) * 64 + (c0 >> 5)) * 512;
    int rt = tid >> 8, s = tid & 255;
    *(short8*)&w2t[tb0 + (size_t)rt * 64 * 512 + s * 8] =
        *(const short8*)&sm[rt * 2048 + s * 8];
    return;
  }

  const int gemmid = (gq * 2 + q3) * 8 + lane8;   // 0..4095, gemmid%8 == bid%8
  const int widx = (gemmid & 7) * 512 + (gemmid >> 3);
  const int mt = widx & 31, e = (widx >> 5) & 7, ft = widx >> 8;
  const int ne = counts[e];
  const int m0 = mt * 128;
  if (m0 >= ne) return;
  const int f0 = ft * 128;
  int hb = 0;
#pragma unroll
  for (int i = 0; i < 7; ++i) if (i < e) hb += (counts[i] + 31) & ~31;
  const int wid = tid >> 6, lane = tid & 63;
  const int wm = wid >> 2, wn = wid & 3;       // 2 x 4 wave grid
  const int lr = lane & 15, lgp = lane >> 4;

  const int rtX0 = (hb + m0) >> 4;
  const ushort* sx = Xg  + ((size_t)(rtX0 + wid) * 16) * 512 + lane * 8;
  const ushort* s1 = w1t + ((size_t)(e * 128 + (f0 >> 4) + wid) * 16) * 512 + lane * 8;
  const ushort* s3 = w3t + ((size_t)(e * 128 + (f0 >> 4) + wid) * 16) * 512 + lane * 8;

  // stage K-step s into buffer s%3; per-wave 1KB per tensor
#define FFN1_STAGE(B)                                                       \
  { char* base = (char*)smem + (B) * 24576 + wid * 1024;                    \
    load16(base, sx);                                                       \
    load16(base + 8192, s1);                                                \
    load16(base + 16384, s3);                                               \
    sx += 512; s1 += 512; s3 += 512; }

#define FFN1_COMPUTE(B)                                                     \
  { const ushort* cb = smem + (B) * 12288;                                  \
    short8 af[4], b1[2], b3[2];                                             \
    _Pragma("unroll")                                                       \
    for (int mf = 0; mf < 4; ++mf)                                          \
      af[mf] = *(const short8*)&cb[(wm * 4 + mf) * 512 + lane * 8];         \
    _Pragma("unroll")                                                       \
    for (int nf = 0; nf < 2; ++nf) {                                        \
      b1[nf] = *(const short8*)&cb[4096 + (wn * 2 + nf) * 512 + lane * 8];  \
      b3[nf] = *(const short8*)&cb[8192 + (wn * 2 + nf) * 512 + lane * 8];  \
    }                                                                       \
    _Pragma("unroll")                                                       \
    for (int mf = 0; mf < 4; ++mf)                                          \
      _Pragma("unroll")                                                     \
      for (int nf = 0; nf < 2; ++nf) {                                      \
        acc1[mf][nf] = __builtin_amdgcn_mfma_f32_16x16x32_bf16(             \
            af[mf], b1[nf], acc1[mf][nf], 0, 0, 0);                         \
        acc3[mf][nf] = __builtin_amdgcn_mfma_f32_16x16x32_bf16(             \
            af[mf], b3[nf], acc3[mf][nf], 0, 0, 0);                         \
      } }

  floatx4 acc1[4][2], acc3[4][2];
#pragma unroll
  for (int a = 0; a < 4; ++a)
#pragma unroll
    for (int b = 0; b < 2; ++b) { acc1[a][b] = (floatx4)0.f; acc3[a][b] = (floatx4)0.f; }

  // depth-2 counted-vmcnt pipeline. 3 loads/stage/wave; at the wait point
  // stages {t, t+1, t+2} are outstanding (9 loads) -> vmcnt(6) drains stage t.
  FFN1_STAGE(0);
  FFN1_STAGE(1);
#pragma unroll
  for (int t = 0; t < 16; ++t) {                       // K = 512/32
    if (t + 2 < 16) FFN1_STAGE((t + 2) % 3);
    if (t < 14)      asm volatile("s_waitcnt vmcnt(6)" ::: "memory");
    else if (t < 15) asm volatile("s_waitcnt vmcnt(3)" ::: "memory");
    else             asm volatile("s_waitcnt vmcnt(0)" ::: "memory");
    BAR(); SBAR();
    __builtin_amdgcn_s_setprio(1);
    FFN1_COMPUTE(t % 3);
    __builtin_amdgcn_s_setprio(0);
    SBAR(); BAR();
  }

  // epilogue: write H in fragment-tiled layout (KT=64)
#pragma unroll
  for (int mf = 0; mf < 4; ++mf) {
    const int rtOut = rtX0 + wm * 4 + mf;
#pragma unroll
    for (int nf = 0; nf < 2; ++nf) {
      const int kt = (f0 >> 5) + wn;
      const int slotc = (nf * 2 + (lr >> 3)) & 3;
      size_t base = ((size_t)rtOut * 64 + kt) * 512 + 16 * slotc * 8 + (lr & 7);
      floatx4 v1 = acc1[mf][nf], v3 = acc3[mf][nf];
#pragma unroll
      for (int j = 0; j < 4; ++j) {
        int p = m0 + wm * 64 + mf * 16 + lgp * 4 + j;
        if (p < ne) {
          float h1 = v1[j], h3 = v3[j];
          float sig = 1.f / (1.f + __expf(-h1));
          H[base + (size_t)(lgp * 4 + j) * 8] = f2b(h1 * sig * h3);
        }
      }
    }
  }
#undef FFN1_STAGE
#undef FFN1_COMPUTE
}

// ---------------- GEMM2: Y = H W2^T, BK=64, K-split 2, counted-vmcnt + setprio
__global__ __launch_bounds__(512) void k_ffn2(
    const ushort* __restrict__ Ht, const ushort* __restrict__ w2t,
    const int* __restrict__ counts, const int* __restrict__ lists,
    const float* __restrict__ wts, float* __restrict__ out)
{
  const int bid = blockIdx.x;                  // nwg = 2048
  const int widx = (bid & 7) * 256 + (bid >> 3);
  const int mt = widx & 31, e = (widx >> 5) & 7;
  const int rest = widx >> 8;                  // 0..7
  const int dt = rest & 3, ks = rest >> 2;
  const int ne = counts[e];
  const int m0 = mt * 128;
  if (m0 >= ne) return;
  const int d0 = dt * 128;
  int hb = 0;
#pragma unroll
  for (int i = 0; i < 7; ++i) if (i < e) hb += (counts[i] + 31) & ~31;
  const int tid = threadIdx.x;
  const int wid = tid >> 6, lane = tid & 63;
  const int wm = wid >> 2, wn = wid & 3;
  const int lr = lane & 15, lgp = lane >> 4;

  __shared__ ushort Hls[2][8192], W2ls[2][8192];
  __shared__ int toks[128];
  __shared__ float twt[128];

  if (tid < 128) {
    int p = m0 + tid;
    bool v = p < ne;
    toks[tid] = v ? lists[e * TTOK + p] : 0;
    twt[tid] = v ? wts[e * TTOK + p] : 0.f;
  }

  const int rtH0 = (hb + m0) >> 4;
  const int kb = ks * 32;                      // K-tile base (32-col units)
  const ushort* sh = Ht  + ((size_t)(rtH0 + wid) * 64 + kb) * 512 + lane * 8;
  const ushort* sw = w2t + ((size_t)(e * 32 + (d0 >> 4) + wid) * 64 + kb) * 512 + lane * 8;

#define FFN2_STAGE(B)                                                      \
  { load16((char*)&Hls[B][0]  + (wid * 2) * 1024, sh);                     \
    load16((char*)&Hls[B][0]  + (wid * 2 + 1) * 1024, sh + 512);           \
    load16((char*)&W2ls[B][0] + (wid * 2) * 1024, sw);                     \
    load16((char*)&W2ls[B][0] + (wid * 2 + 1) * 1024, sw + 512);           \
    sh += 1024; sw += 1024; }

#define FFN2_COMPUTE(B)                                                    \
  { _Pragma("unroll")                                                      \
    for (int kk = 0; kk < 2; ++kk) {                                       \
      short8 af[4], bf[2];                                                 \
      _Pragma("unroll")                                                    \
      for (int mf = 0; mf < 4; ++mf)                                       \
        af[mf] = *(const short8*)&Hls[B][((wm * 4 + mf) * 2 + kk) * 512 + lane * 8]; \
      _Pragma("unroll")                                                    \
      for (int nf = 0; nf < 2; ++nf)                                       \
        bf[nf] = *(const short8*)&W2ls[B][((wn * 2 + nf) * 2 + kk) * 512 + lane * 8]; \
      _Pragma("unroll")                                                    \
      for (int mf = 0; mf < 4; ++mf)                                       \
        _Pragma("unroll")                                                  \
        for (int nf = 0; nf < 2; ++nf)                                     \
          acc[mf][nf] = __builtin_amdgcn_mfma_f32_16x16x32_bf16(           \
              af[mf], bf[nf], acc[mf][nf], 0, 0, 0);                       \
    } }

  floatx4 acc[4][2];
#pragma unroll
  for (int a = 0; a < 4; ++a)
#pragma unroll
    for (int b = 0; b < 2; ++b) acc[a][b] = (floatx4)0.f;

  FFN2_STAGE(0);
  for (int t = 0; t < 16; t += 2) {            // K = 1024/64 per split
    FFN2_STAGE(1);
    asm volatile("s_waitcnt vmcnt(4)" ::: "memory");
    BAR(); SBAR();
    __builtin_amdgcn_s_setprio(1);
    FFN2_COMPUTE(0);
    __builtin_amdgcn_s_setprio(0);
    SBAR(); BAR();
    if (t + 2 < 16) {
      FFN2_STAGE(0);
      asm volatile("s_waitcnt vmcnt(4)" ::: "memory");
    } else {
      asm volatile("s_waitcnt vmcnt(0)" ::: "memory");
    }
    BAR(); SBAR();
    __builtin_amdgcn_s_setprio(1);
    FFN2_COMPUTE(1);
    __builtin_amdgcn_s_setprio(0);
    SBAR(); BAR();
  }

#pragma unroll
  for (int mf = 0; mf < 4; ++mf) {
#pragma unroll
    for (int j = 0; j < 4; ++j) {
      int rloc = wm * 64 + mf * 16 + lgp * 4 + j;
      int p = m0 + rloc;
      if (p < ne) {
        int t = toks[rloc];
        float w = twt[rloc];
#pragma unroll
        for (int nf = 0; nf < 2; ++nf) {
          int d = d0 + wn * 32 + nf * 16 + lr;
          atomicAdd(&out[(size_t)t * DDIM + d], w * acc[mf][nf][j]);
        }
      }
    }
  }
#undef FFN2_STAGE
#undef FFN2_COMPUTE
}

extern "C" void kernel_launch(void* const* d_in, const int* in_sizes, int n_in,
                              void* d_out, int out_size, void* d_ws, size_t ws_size,
                              hipStream_t stream) {
  const float* x  = (const float*)d_in[0];
  const float* gw = (const float*)d_in[1];
  const float* w1 = (const float*)d_in[2];
  const float* w2 = (const float*)d_in[3];
  const float* w3 = (const float*)d_in[4];
  float* out = (float*)d_out;
  float* logits = out + (size_t)TTOK * DDIM;

  // workspace layout (~94.6 MB)
  int* counts = (int*)d_ws;                        // [8] (pad to 16)
  int* tok_e  = counts + 16;                       // [4096]
  float2* tok_w = (float2*)(tok_e + TTOK);         // [4096]
  int* lists  = (int*)(tok_w + TTOK);              // [8][4096]
  float* wts  = (float*)(lists + NEXP * TTOK);     // [8][4096]
  ushort* w1t = (ushort*)(wts + NEXP * TTOK);      // tiled
  ushort* w3t = w1t + (size_t)NEXP * FDIM * DDIM;
  ushort* w2t = w3t + (size_t)NEXP * FDIM * DDIM;  // tiled
  ushort* Xg  = w2t + (size_t)NEXP * DDIM * FDIM;  // tiled [HROWS][512]
  ushort* H   = Xg + (size_t)HROWS * DDIM;         // tiled [HROWS][2048]

  k_front<<<TTOK / 4 + 4096, 256, 0, stream>>>(x, gw, logits, tok_e, tok_w,
                                               out, w1, w1t, w3, w3t);
  k_build<<<NEXP, 1024, 0, stream>>>(tok_e, tok_w, counts, lists, wts);
  k_gather<<<(8448 * 64) / 256, 256, 0, stream>>>(x, counts, lists, Xg);

  k_ffn1<<<4096 + 2048, 512, 0, stream>>>(Xg, w1t, w3t, counts, H, w2, w2t);
  k_ffn2<<<2048, 512, 0, stream>>>(H, w2t, counts, lists, wts, out);
}

// Round 16
// 138.522 us; speedup vs baseline: 1.0083x; 1.0083x over previous
//
#include <hip/hip_runtime.h>

#define TTOK 4096
#define NEXP 8
#define DDIM 512
#define FDIM 2048
#define HROWS 8576   // padded-compact row allocation (max used 8440 + slack)

typedef __attribute__((ext_vector_type(8))) short short8;
typedef __attribute__((ext_vector_type(4))) float floatx4;

#define BAR()  __builtin_amdgcn_s_barrier()
#define SBAR() __builtin_amdgcn_sched_barrier(0)

__device__ __forceinline__ ushort f2b(float f) {
  unsigned u = __float_as_uint(f);
  u += 0x7fffu + ((u >> 16) & 1u);   // round-to-nearest-even bf16
  return (ushort)(u >> 16);
}

__device__ __forceinline__ void load16(void* lds, const void* g) {
  __builtin_amdgcn_global_load_lds(
      (const __attribute__((address_space(1))) unsigned int*)g,
      (__attribute__((address_space(3))) unsigned int*)lds, 16, 0, 0);
}

// Fragment-tile layout (16x16x32 MFMA operands): matrix [R][C] stored as
// 16-row x 32-col tiles of 1KB. Tile (rt,kt) at ((rt*(C/32))+kt)*512 elems.
// elem (r,c): slot = (r&15) + 16*((c>>3)&3), ushort idx = slot*8+(c&7).
// Wave fragment read = lane l reads tile+l*16B -> conflict-free ds_read_b128.

// ---------------- fat front: logits+top2+zero-out (blocks 0..1023) | w1/w3 cvt
__global__ __launch_bounds__(256) void k_front(
    const float* __restrict__ x, const float* __restrict__ gw,
    float* __restrict__ logits, int* __restrict__ tok_e,
    float2* __restrict__ tok_w, float* __restrict__ outz,
    const float* __restrict__ w1, ushort* __restrict__ w1t,
    const float* __restrict__ w3, ushort* __restrict__ w3t)
{
  __shared__ ushort sm[4096];
  const int tid = threadIdx.x;
  if (blockIdx.x < TTOK / 4) {
    // zero the out rows for these 4 tokens (replaces hipMemsetAsync)
    float4 zz = {0.f, 0.f, 0.f, 0.f};
    float4* orow = (float4*)(outz + (size_t)blockIdx.x * 4 * DDIM);
    orow[tid] = zz;
    orow[tid + 256] = zz;
    const int lane = tid & 63;
    const int t = blockIdx.x * 4 + (tid >> 6);
    float xv[8];
#pragma unroll
    for (int i = 0; i < 8; ++i) xv[i] = x[(size_t)t * DDIM + lane + 64 * i];
    float lg[8];
#pragma unroll
    for (int e = 0; e < 8; ++e) {
      float a = 0.f;
#pragma unroll
      for (int i = 0; i < 8; ++i) a += xv[i] * gw[e * DDIM + lane + 64 * i];
#pragma unroll
      for (int s = 32; s; s >>= 1) a += __shfl_xor(a, s, 64);
      lg[e] = a;
    }
    if (lane < 8) logits[(size_t)t * 8 + lane] = lg[lane];
    if (lane == 0) {
      int i0 = 0; float v0 = lg[0];
#pragma unroll
      for (int e = 1; e < 8; ++e) { if (lg[e] > v0) { v0 = lg[e]; i0 = e; } }
      int i1 = -1; float v1 = -3.4e38f;
#pragma unroll
      for (int e = 0; e < 8; ++e) { if (e != i0 && lg[e] > v1) { v1 = lg[e]; i1 = e; } }
      float ex = expf(v1 - v0);
      float inv = 1.f / (1.f + ex);
      tok_e[t] = i0 | (i1 << 4);
      tok_w[t] = make_float2(inv, ex * inv);
    }
    return;
  }
  // w1 / w3 conversion into fragment-tiled layout (C = 512, KT = 16)
  int bid = blockIdx.x - TTOK / 4;             // 0..4095
  const float* src = (bid < 2048) ? w1 : w3;
  ushort* dst = (bid < 2048) ? w1t : w3t;
  if (bid >= 2048) bid -= 2048;
  const int r0 = (bid >> 2) * 32;
  const int c0 = (bid & 3) * 128;
#pragma unroll
  for (int i = 0; i < 4; ++i) {
    int j = i * 1024 + tid * 4;
    int lr = j >> 7, lc = j & 127;
    float4 v = *(const float4*)&src[(size_t)(r0 + lr) * 512 + c0 + lc];
    ushort4 b = { f2b(v.x), f2b(v.y), f2b(v.z), f2b(v.w) };
    int ord = (lr >> 4) * 4 + (lc >> 5);
    int slot = (lr & 15) + 16 * ((lc >> 3) & 3);
    *(ushort4*)&sm[(ord * 64 + slot) * 8 + (lc & 7)] = b;
  }
  __syncthreads();
  const size_t tb0 = ((size_t)(r0 >> 4) * 16 + (c0 >> 5)) * 512;
#pragma unroll
  for (int rt = 0; rt < 2; ++rt)
    *(short8*)&dst[tb0 + (size_t)rt * 16 * 512 + tid * 8] =
        *(const short8*)&sm[rt * 2048 + tid * 8];
}

// ---------------- router pass 2: per-expert compaction, ballot prefix
__global__ __launch_bounds__(1024) void k_build(
    const int* __restrict__ tok_e, const float2* __restrict__ tok_w,
    int* __restrict__ counts, int* __restrict__ lists, float* __restrict__ wts)
{
  const int e = blockIdx.x;
  const int tid = threadIdx.x;
  const int lane = tid & 63, wid = tid >> 6;
  __shared__ int wcnt[16];
  __shared__ int sbase;
  if (tid == 0) sbase = 0;
  __syncthreads();

  for (int c = 0; c < TTOK; c += 1024) {
    int t = c + tid;
    int pe = tok_e[t];
    bool m0 = (pe & 15) == e;
    bool m1 = ((pe >> 4) & 15) == e;
    bool m = m0 || m1;
    unsigned long long b = __ballot(m);
    int lpre = __popcll(b & ((1ull << lane) - 1ull));
    if (lane == 0) wcnt[wid] = __popcll(b);
    __syncthreads();
    int woff = 0;
#pragma unroll
    for (int i = 0; i < 16; ++i) if (i < wid) woff += wcnt[i];
    if (m) {
      float2 w = tok_w[t];
      int pos = sbase + woff + lpre;
      lists[e * TTOK + pos] = t;
      wts[e * TTOK + pos] = m0 ? w.x : w.y;
    }
    __syncthreads();
    if (tid == 0) {
      int s = 0;
#pragma unroll
      for (int i = 0; i < 16; ++i) s += wcnt[i];
      sbase += s;
    }
    __syncthreads();
  }
  if (tid == 0) counts[e] = sbase;
}

// ---------------- gather + f32->bf16: x rows -> compacted fragment-tiled Xg
__global__ __launch_bounds__(256) void k_gather(
    const float* __restrict__ x, const int* __restrict__ counts,
    const int* __restrict__ lists, ushort* __restrict__ Xg)
{
  int pp[9];
  pp[0] = 0;
#pragma unroll
  for (int i = 0; i < 8; ++i) pp[i + 1] = pp[i] + ((counts[i] + 31) & ~31);
  int gid = blockIdx.x * 256 + threadIdx.x;
  int gr = gid >> 6, dg = gid & 63;        // row, 8-col group
  if (gr >= pp[8]) return;
  int e = 0;
  while (e < 7 && gr >= pp[e + 1]) ++e;
  int p = gr - pp[e];
  size_t dst = ((size_t)(gr >> 4) * 16 + (dg >> 2)) * 512
             + ((gr & 15) + 16 * (dg & 3)) * 8;
  short8 o = (short8)0;
  if (p < counts[e]) {
    int t = lists[e * TTOK + p];
    const float* s = x + (size_t)t * DDIM + dg * 8;
    float4 a = *(const float4*)s;
    float4 b = *(const float4*)(s + 4);
    o[0] = f2b(a.x); o[1] = f2b(a.y); o[2] = f2b(a.z); o[3] = f2b(a.w);
    o[4] = f2b(b.x); o[5] = f2b(b.y); o[6] = f2b(b.z); o[7] = f2b(b.w);
  }
  *(short8*)&Xg[dst] = o;
}

// ---------------- fat GEMM1: H = silu(Xg W1^T) * (Xg W3^T)
//                  + w2 cvt, INTERLEAVED (1 cvt 8-round per 2 gemm 8-rounds)
// 8 waves (2x4), 128x128 tile, BK=32, TRIPLE-buffered (depth-2 prefetch),
// counted-vmcnt pipeline, fragment-tiled LDS (conflict-free),
// LDS-staged coalesced H epilogue
__global__ __launch_bounds__(512) void k_ffn1(
    const ushort* __restrict__ Xg, const ushort* __restrict__ w1t,
    const ushort* __restrict__ w3t, const int* __restrict__ counts,
    ushort* __restrict__ H,
    const float* __restrict__ w2, ushort* __restrict__ w2t)
{
  // 3 buffers x (X 8KB | W1 8KB | W3 8KB) = 72KB
  __shared__ ushort smem[36864];
  const int tid = threadIdx.x;

  // role by 8-block round: rounds 0,1 of each 3 -> GEMM; round 2 -> w2 cvt.
  const int grp = blockIdx.x >> 3, lane8 = blockIdx.x & 7;
  const int q3 = grp % 3, gq = grp / 3;

  if (q3 == 2) {
    // ---- w2 conversion path (C = 2048, KT = 64), 512 threads
    int bid = gq * 8 + lane8;                  // 0..2047
    ushort* sm = smem;
    const int r0 = (bid >> 4) * 32;
    const int c0 = (bid & 15) * 128;
#pragma unroll
    for (int i = 0; i < 2; ++i) {
      int j = i * 2048 + tid * 4;
      int lr = j >> 7, lc = j & 127;
      float4 v = *(const float4*)&w2[(size_t)(r0 + lr) * 2048 + c0 + lc];
      ushort4 b = { f2b(v.x), f2b(v.y), f2b(v.z), f2b(v.w) };
      int ord = (lr >> 4) * 4 + (lc >> 5);
      int slot = (lr & 15) + 16 * ((lc >> 3) & 3);
      *(ushort4*)&sm[(ord * 64 + slot) * 8 + (lc & 7)] = b;
    }
    __syncthreads();
    const size_t tb0 = ((size_t)(r0 >> 4) * 64 + (c0 >> 5)) * 512;
    int rt = tid >> 8, s = tid & 255;
    *(short8*)&w2t[tb0 + (size_t)rt * 64 * 512 + s * 8] =
        *(const short8*)&sm[rt * 2048 + s * 8];
    return;
  }

  const int gemmid = (gq * 2 + q3) * 8 + lane8;   // 0..4095, gemmid%8 == bid%8
  const int widx = (gemmid & 7) * 512 + (gemmid >> 3);
  const int mt = widx & 31, e = (widx >> 5) & 7, ft = widx >> 8;
  const int ne = counts[e];
  const int m0 = mt * 128;
  if (m0 >= ne) return;
  const int f0 = ft * 128;
  int hb = 0;
#pragma unroll
  for (int i = 0; i < 7; ++i) if (i < e) hb += (counts[i] + 31) & ~31;
  const int wid = tid >> 6, lane = tid & 63;
  const int wm = wid >> 2, wn = wid & 3;       // 2 x 4 wave grid
  const int lr = lane & 15, lgp = lane >> 4;

  const int rtX0 = (hb + m0) >> 4;
  const ushort* sx = Xg  + ((size_t)(rtX0 + wid) * 16) * 512 + lane * 8;
  const ushort* s1 = w1t + ((size_t)(e * 128 + (f0 >> 4) + wid) * 16) * 512 + lane * 8;
  const ushort* s3 = w3t + ((size_t)(e * 128 + (f0 >> 4) + wid) * 16) * 512 + lane * 8;

  // stage K-step s into buffer s%3; per-wave 1KB per tensor
#define FFN1_STAGE(B)                                                       \
  { char* base = (char*)smem + (B) * 24576 + wid * 1024;                    \
    load16(base, sx);                                                       \
    load16(base + 8192, s1);                                                \
    load16(base + 16384, s3);                                               \
    sx += 512; s1 += 512; s3 += 512; }

#define FFN1_COMPUTE(B)                                                     \
  { const ushort* cb = smem + (B) * 12288;                                  \
    short8 af[4], b1[2], b3[2];                                             \
    _Pragma("unroll")                                                       \
    for (int mf = 0; mf < 4; ++mf)                                          \
      af[mf] = *(const short8*)&cb[(wm * 4 + mf) * 512 + lane * 8];         \
    _Pragma("unroll")                                                       \
    for (int nf = 0; nf < 2; ++nf) {                                        \
      b1[nf] = *(const short8*)&cb[4096 + (wn * 2 + nf) * 512 + lane * 8];  \
      b3[nf] = *(const short8*)&cb[8192 + (wn * 2 + nf) * 512 + lane * 8];  \
    }                                                                       \
    _Pragma("unroll")                                                       \
    for (int mf = 0; mf < 4; ++mf)                                          \
      _Pragma("unroll")                                                     \
      for (int nf = 0; nf < 2; ++nf) {                                      \
        acc1[mf][nf] = __builtin_amdgcn_mfma_f32_16x16x32_bf16(             \
            af[mf], b1[nf], acc1[mf][nf], 0, 0, 0);                         \
        acc3[mf][nf] = __builtin_amdgcn_mfma_f32_16x16x32_bf16(             \
            af[mf], b3[nf], acc3[mf][nf], 0, 0, 0);                         \
      } }

  floatx4 acc1[4][2], acc3[4][2];
#pragma unroll
  for (int a = 0; a < 4; ++a)
#pragma unroll
    for (int b = 0; b < 2; ++b) { acc1[a][b] = (floatx4)0.f; acc3[a][b] = (floatx4)0.f; }

  // depth-2 counted-vmcnt pipeline. 3 loads/stage/wave; at the wait point
  // stages {t, t+1, t+2} are outstanding (9 loads) -> vmcnt(6) drains stage t.
  FFN1_STAGE(0);
  FFN1_STAGE(1);
#pragma unroll
  for (int t = 0; t < 16; ++t) {                       // K = 512/32
    if (t + 2 < 16) FFN1_STAGE((t + 2) % 3);
    if (t < 14)      asm volatile("s_waitcnt vmcnt(6)" ::: "memory");
    else if (t < 15) asm volatile("s_waitcnt vmcnt(3)" ::: "memory");
    else             asm volatile("s_waitcnt vmcnt(0)" ::: "memory");
    BAR(); SBAR();
    FFN1_COMPUTE(t % 3);
    SBAR(); BAR();
  }

  // epilogue: silu*mul -> stage H tile (128x128) in LDS fragment-tile layout,
  // then coalesced short8 stores (row-guarded).
  __syncthreads();                    // all waves done with staging buffers
  ushort* hstage = smem;              // reuse 32KB of the 72KB staging LDS
#pragma unroll
  for (int mf = 0; mf < 4; ++mf) {
#pragma unroll
    for (int nf = 0; nf < 2; ++nf) {
      const int tloc = (wm * 4 + mf) * 4 + wn;        // local tile 0..31
      const int slotc = (nf * 2 + (lr >> 3)) & 3;
      const int bidx = tloc * 512 + slotc * 128 + (lr & 7);
      floatx4 v1 = acc1[mf][nf], v3 = acc3[mf][nf];
#pragma unroll
      for (int j = 0; j < 4; ++j) {
        float h1 = v1[j], h3 = v3[j];
        float sig = 1.f / (1.f + __expf(-h1));
        hstage[bidx + (lgp * 4 + j) * 8] = f2b(h1 * sig * h3);
      }
    }
  }
  __syncthreads();
  const int ktBase = f0 >> 5;
#pragma unroll
  for (int i = 0; i < 4; ++i) {
    int s = i * 512 + tid;            // short8 index 0..2047
    int tloc = s >> 6, off = s & 63;  // tile, slot
    int rt_l = tloc >> 2, kt_l = tloc & 3;
    if (m0 + rt_l * 16 + (off & 15) < ne)
      *(short8*)&H[((size_t)(rtX0 + rt_l) * 64 + ktBase + kt_l) * 512 + off * 8] =
          *(const short8*)&hstage[s * 8];
  }
#undef FFN1_STAGE
#undef FFN1_COMPUTE
}

// ---------------- GEMM2: Y = H W2^T, BK=64, K-split 2, R9 counted-vmcnt
__global__ __launch_bounds__(512) void k_ffn2(
    const ushort* __restrict__ Ht, const ushort* __restrict__ w2t,
    const int* __restrict__ counts, const int* __restrict__ lists,
    const float* __restrict__ wts, float* __restrict__ out)
{
  const int bid = blockIdx.x;                  // nwg = 2048
  const int widx = (bid & 7) * 256 + (bid >> 3);
  const int mt = widx & 31, e = (widx >> 5) & 7;
  const int rest = widx >> 8;                  // 0..7
  const int dt = rest & 3, ks = rest >> 2;
  const int ne = counts[e];
  const int m0 = mt * 128;
  if (m0 >= ne) return;
  const int d0 = dt * 128;
  int hb = 0;
#pragma unroll
  for (int i = 0; i < 7; ++i) if (i < e) hb += (counts[i] + 31) & ~31;
  const int tid = threadIdx.x;
  const int wid = tid >> 6, lane = tid & 63;
  const int wm = wid >> 2, wn = wid & 3;
  const int lr = lane & 15, lgp = lane >> 4;

  __shared__ ushort Hls[2][8192], W2ls[2][8192];
  __shared__ int toks[128];
  __shared__ float twt[128];

  if (tid < 128) {
    int p = m0 + tid;
    bool v = p < ne;
    toks[tid] = v ? lists[e * TTOK + p] : 0;
    twt[tid] = v ? wts[e * TTOK + p] : 0.f;
  }

  const int rtH0 = (hb + m0) >> 4;
  const int kb = ks * 32;                      // K-tile base (32-col units)
  const ushort* sh = Ht  + ((size_t)(rtH0 + wid) * 64 + kb) * 512 + lane * 8;
  const ushort* sw = w2t + ((size_t)(e * 32 + (d0 >> 4) + wid) * 64 + kb) * 512 + lane * 8;

#define FFN2_STAGE(B)                                                      \
  { load16((char*)&Hls[B][0]  + (wid * 2) * 1024, sh);                     \
    load16((char*)&Hls[B][0]  + (wid * 2 + 1) * 1024, sh + 512);           \
    load16((char*)&W2ls[B][0] + (wid * 2) * 1024, sw);                     \
    load16((char*)&W2ls[B][0] + (wid * 2 + 1) * 1024, sw + 512);           \
    sh += 1024; sw += 1024; }

#define FFN2_COMPUTE(B)                                                    \
  { _Pragma("unroll")                                                      \
    for (int kk = 0; kk < 2; ++kk) {                                       \
      short8 af[4], bf[2];                                                 \
      _Pragma("unroll")                                                    \
      for (int mf = 0; mf < 4; ++mf)                                       \
        af[mf] = *(const short8*)&Hls[B][((wm * 4 + mf) * 2 + kk) * 512 + lane * 8]; \
      _Pragma("unroll")                                                    \
      for (int nf = 0; nf < 2; ++nf)                                       \
        bf[nf] = *(const short8*)&W2ls[B][((wn * 2 + nf) * 2 + kk) * 512 + lane * 8]; \
      _Pragma("unroll")                                                    \
      for (int mf = 0; mf < 4; ++mf)                                       \
        _Pragma("unroll")                                                  \
        for (int nf = 0; nf < 2; ++nf)                                     \
          acc[mf][nf] = __builtin_amdgcn_mfma_f32_16x16x32_bf16(           \
              af[mf], bf[nf], acc[mf][nf], 0, 0, 0);                       \
    } }

  floatx4 acc[4][2];
#pragma unroll
  for (int a = 0; a < 4; ++a)
#pragma unroll
    for (int b = 0; b < 2; ++b) acc[a][b] = (floatx4)0.f;

  FFN2_STAGE(0);
  for (int t = 0; t < 16; t += 2) {            // K = 1024/64 per split
    FFN2_STAGE(1);
    asm volatile("s_waitcnt vmcnt(4)" ::: "memory");
    BAR(); SBAR();
    FFN2_COMPUTE(0);
    SBAR(); BAR();
    if (t + 2 < 16) {
      FFN2_STAGE(0);
      asm volatile("s_waitcnt vmcnt(4)" ::: "memory");
    } else {
      asm volatile("s_waitcnt vmcnt(0)" ::: "memory");
    }
    BAR(); SBAR();
    FFN2_COMPUTE(1);
    SBAR(); BAR();
  }

#pragma unroll
  for (int mf = 0; mf < 4; ++mf) {
#pragma unroll
    for (int j = 0; j < 4; ++j) {
      int rloc = wm * 64 + mf * 16 + lgp * 4 + j;
      int p = m0 + rloc;
      if (p < ne) {
        int t = toks[rloc];
        float w = twt[rloc];
#pragma unroll
        for (int nf = 0; nf < 2; ++nf) {
          int d = d0 + wn * 32 + nf * 16 + lr;
          atomicAdd(&out[(size_t)t * DDIM + d], w * acc[mf][nf][j]);
        }
      }
    }
  }
#undef FFN2_STAGE
#undef FFN2_COMPUTE
}

extern "C" void kernel_launch(void* const* d_in, const int* in_sizes, int n_in,
                              void* d_out, int out_size, void* d_ws, size_t ws_size,
                              hipStream_t stream) {
  const float* x  = (const float*)d_in[0];
  const float* gw = (const float*)d_in[1];
  const float* w1 = (const float*)d_in[2];
  const float* w2 = (const float*)d_in[3];
  const float* w3 = (const float*)d_in[4];
  float* out = (float*)d_out;
  float* logits = out + (size_t)TTOK * DDIM;

  // workspace layout (~94.6 MB)
  int* counts = (int*)d_ws;                        // [8] (pad to 16)
  int* tok_e  = counts + 16;                       // [4096]
  float2* tok_w = (float2*)(tok_e + TTOK);         // [4096]
  int* lists  = (int*)(tok_w + TTOK);              // [8][4096]
  float* wts  = (float*)(lists + NEXP * TTOK);     // [8][4096]
  ushort* w1t = (ushort*)(wts + NEXP * TTOK);      // tiled
  ushort* w3t = w1t + (size_t)NEXP * FDIM * DDIM;
  ushort* w2t = w3t + (size_t)NEXP * FDIM * DDIM;  // tiled
  ushort* Xg  = w2t + (size_t)NEXP * DDIM * FDIM;  // tiled [HROWS][512]
  ushort* H   = Xg + (size_t)HROWS * DDIM;         // tiled [HROWS][2048]

  k_front<<<TTOK / 4 + 4096, 256, 0, stream>>>(x, gw, logits, tok_e, tok_w,
                                               out, w1, w1t, w3, w3t);
  k_build<<<NEXP, 1024, 0, stream>>>(tok_e, tok_w, counts, lists, wts);
  k_gather<<<(8448 * 64) / 256, 256, 0, stream>>>(x, counts, lists, Xg);

  k_ffn1<<<4096 + 2048, 512, 0, stream>>>(Xg, w1t, w3t, counts, H, w2, w2t);
  k_ffn2<<<2048, 512, 0, stream>>>(H, w2t, counts, lists, wts, out);
}